// Round 7
// baseline (152.627 us; speedup 1.0000x reference)
//
#include <hip/hip_runtime.h>
#include <math.h>

// Static graph dims
#define BATCH   16384
#define IN_DIM  512
#define NH      128
#define NO      256
#define L2E     1.4426950408889634f

__device__ __forceinline__ float fast_rcp(float x) { return __builtin_amdgcn_rcpf(x); }
__device__ __forceinline__ float fast_exp2(float x) {
#if __has_builtin(__builtin_amdgcn_exp2f)
    return __builtin_amdgcn_exp2f(x);
#else
    return exp2f(x);
#endif
}
__device__ __forceinline__ int rfl(int v) { return __builtin_amdgcn_readfirstlane(v); }
__device__ __forceinline__ int rdl(int v, int l) { return __builtin_amdgcn_readlane(v, l); }

__device__ __forceinline__ float fast_tanh(float z) {
    float ex = fast_exp2(2.f * L2E * z);
    return 1.f - 2.f * fast_rcp(1.f + ex);
}
__device__ __forceinline__ float act_k(int a) {
    return (a == 2) ? (2.f * L2E) : ((a == 4) ? -L2E : 0.f);
}

__device__ __forceinline__ unsigned int f2bf_rne(float f) {
    unsigned int u = __float_as_uint(f);
    return (u + 0x7FFFu + ((u >> 16) & 1u)) >> 16;
}
__device__ __forceinline__ float bf2f(unsigned short h) { return __uint_as_float(((unsigned int)h) << 16); }
__device__ __forceinline__ unsigned short f2bf16s(float f) { return (unsigned short)f2bf_rne(f); }

__device__ __forceinline__ int lower_bound_dev(const int* __restrict__ arr, int n, int v) {
    int lo = 0, hi = n;
    while (lo < hi) { int m = (lo + hi) >> 1; if (arr[m] < v) lo = m + 1; else hi = m; }
    return lo;
}
__device__ __forceinline__ int imin(int a, int b) { return a < b ? a : b; }
__device__ __forceinline__ int imax(int a, int b) { return a > b ? a : b; }

#define FXS     514
#define FHS     65
#define MLDS    99072
#define RSU     128     // u32 slots per row record (512 B)
#define FASTN   60      // edges 0..59 at slots 3..62; edges 60.. at slots 64..127

// ---------------- prep: per-row records, 8-way (act x src) sorted, SEGMENTS PADDED to x4 ----
// slot 0: c1|c2<<8|c3<<16|c4<<24   slot 1: c5|c6<<8|c7<<16|n_p<<24  (PADDED cumulative bounds)
// slot 2: f32 init = (#tanh slots in fast region) - 0.5*(#sigmoid dummies)  [exact compensation]
// slot 3+j (j<60) / 64+(j-60): edge j = [w22 | off10]; dummies have payload 0.
__global__ __launch_bounds__(512)
void prep_rows(const int* __restrict__ rows_h, const int* __restrict__ cols_h,
               const int* __restrict__ acts_h, const float* __restrict__ wh,
               const int* __restrict__ rows_o, const int* __restrict__ cols_o,
               const int* __restrict__ acts_o, const float* __restrict__ wo,
               int Eh, int Eo, unsigned* __restrict__ rrh, unsigned* __restrict__ rro)
{
    const int lane = (int)(threadIdx.x & 63);
    const int wid  = (int)((blockIdx.x * 512 + threadIdx.x) >> 6);
    if (wid >= NH + NO) return;
    const bool isH = wid < NH;
    const int r = isH ? wid : wid - NH;
    const int*   rows = isH ? rows_h : rows_o;
    const int*   cols = isH ? cols_h : cols_o;
    const int*   acts = isH ? acts_h : acts_o;
    const float* ww   = isH ? wh : wo;
    const int    E    = isH ? Eh : Eo;
    unsigned* rec = (isH ? rrh : rro) + (size_t)r * RSU;

    const int e0 = lower_bound_dev(rows, E, r);
    const int e1 = lower_bound_dev(rows, E, r + 1);
    int n = e1 - e0; if (n > 100) n = 100;          // memory-safety clamp (unreachable)
    const unsigned long long lt = (1ull << lane) - 1ull;

    int cnt[8] = {0,0,0,0,0,0,0,0};
    for (int g = 0; g < n; g += 64) {
        int seg = -1;
        if (g + lane < n) {
            int e = e0 + g + lane;
            int a = acts[e];
            int col = cols[e];
            seg = (a - 1) + ((!isH && col >= IN_DIM) ? 4 : 0);
        }
        #pragma unroll
        for (int s = 0; s < 8; ++s) cnt[s] += __popcll(__ballot(seg == s));
    }
    int cntp[8], cum[9]; cum[0] = 0;
    #pragma unroll
    for (int s = 0; s < 8; ++s) { cntp[s] = (cnt[s] + 3) & ~3; cum[s + 1] = cum[s] + cntp[s]; }
    const int np = cum[8];                           // <= 124

    // init constant: +1 per tanh SLOT in fast region (dummies self-cancel via fmac(-2,0.5));
    // -0.5 per sigmoid dummy (anywhere) to cancel its exact rcp(2)=0.5 contribution.
    int t = 0;
    t += imax(0, imin(cum[1] + cntp[1], FASTN) - imin(cum[1], FASTN));
    t += imax(0, imin(cum[5] + cntp[5], FASTN) - imin(cum[5], FASTN));
    int d4 = (cntp[3] - cnt[3]) + (cntp[7] - cnt[7]);
    float initf = (float)t - 0.5f * (float)d4;

    if (lane == 0) {
        rec[0] = (unsigned)cum[1] | ((unsigned)cum[2] << 8) | ((unsigned)cum[3] << 16) | ((unsigned)cum[4] << 24);
        rec[1] = (unsigned)cum[5] | ((unsigned)cum[6] << 8) | ((unsigned)cum[7] << 16) | ((unsigned)np << 24);
        rec[2] = __float_as_uint(initf);
    }

    int pos[8];
    #pragma unroll
    for (int s = 0; s < 8; ++s) pos[s] = cum[s];
    for (int g = 0; g < n; g += 64) {
        int seg = -1; unsigned payload = 0;
        if (g + lane < n) {
            int e = e0 + g + lane;
            int a = acts[e];
            int col = cols[e];
            bool hs = (!isH && col >= IN_DIM);
            seg = (a - 1) + (hs ? 4 : 0);
            unsigned offv = hs ? (unsigned)(col - IN_DIM) : (unsigned)col;   // < 1024
            float w = ww[e];
            float ws = (a == 2) ? (2.f * L2E) * w : ((a == 4) ? -L2E * w : w);
            unsigned wb = (__float_as_uint(ws) + 0x200u) & 0xFFFFFC00u;      // RN to 22 bits
            payload = wb | offv;
        }
        #pragma unroll
        for (int s = 0; s < 8; ++s) {
            unsigned long long m = __ballot(seg == s);
            if (seg == s) {
                int idx = pos[s] + __popcll(m & lt);
                rec[idx < FASTN ? 3 + idx : 64 + (idx - FASTN)] = payload;
            }
            pos[s] += __popcll(m);
        }
    }
    // dummy slots (payload 0) at each segment tail
    #pragma unroll
    for (int s = 0; s < 8; ++s) {
        int d = cntp[s] - cnt[s];
        if (lane < d) {
            int idx = cum[s] + cnt[s] + lane;
            rec[idx < FASTN ? 3 + idx : 64 + (idx - FASTN)] = 0u;
        }
    }
}

// ---------------- fused main ----------------
// LDS: X bf16 [64][514] = 65792 B + Hf f32 [128][65] = 33280 B -> 99072 B.
// Segments are exact multiples of 4 -> no remainder loops, no per-edge lgkmcnt(0) waits;
// unroll 2 keeps 8 ds_reads in flight. Decode is SALU; 1 v_readlane per edge.
template<int ACT>
__device__ __forceinline__ float app(float acc, float v, float w) {
    if (ACT == 1)      return fmaf(v, w, acc);
    else if (ACT == 2) { float ex = fast_exp2(v * w); return fmaf(-2.f, fast_rcp(1.f + ex), acc); }
    else if (ACT == 3) return acc + fmaxf(v * w, 0.f);
    else               { float ex = fast_exp2(v * w); return acc + fast_rcp(1.f + ex); }
}

template<int ACT, bool HS>
__device__ __forceinline__ void seg_run4(float& a0, float& a1,
                                         const unsigned short* __restrict__ Xl,  // X + lane*FXS
                                         const float* __restrict__ Hl,           // Hf + lane
                                         unsigned hv, int lo, int hi)
{
    #pragma unroll 2
    for (int j = lo; j < hi; j += 4) {
        unsigned s0 = (unsigned)rdl((int)hv, j + 3);
        unsigned s1 = (unsigned)rdl((int)hv, j + 4);
        unsigned s2 = (unsigned)rdl((int)hv, j + 5);
        unsigned s3 = (unsigned)rdl((int)hv, j + 6);
        float v0 = HS ? Hl[(s0 & 1023u) * FHS] : bf2f(Xl[s0 & 1023u]);
        float v1 = HS ? Hl[(s1 & 1023u) * FHS] : bf2f(Xl[s1 & 1023u]);
        float v2 = HS ? Hl[(s2 & 1023u) * FHS] : bf2f(Xl[s2 & 1023u]);
        float v3 = HS ? Hl[(s3 & 1023u) * FHS] : bf2f(Xl[s3 & 1023u]);
        a0 = app<ACT>(a0, v0, __uint_as_float(s0 & 0xFFFFFC00u));
        a1 = app<ACT>(a1, v1, __uint_as_float(s1 & 0xFFFFFC00u));
        a0 = app<ACT>(a0, v2, __uint_as_float(s2 & 0xFFFFFC00u));
        a1 = app<ACT>(a1, v3, __uint_as_float(s3 & 0xFFFFFC00u));
    }
}

template<bool OUT>
__device__ __forceinline__ float row_body(unsigned hv, const unsigned* __restrict__ grow,
                                          const unsigned short* __restrict__ Xl,
                                          const float* __restrict__ Hl, int lane)
{
    const unsigned hx = (unsigned)rdl((int)hv, 0);
    const unsigned hy = (unsigned)rdl((int)hv, 1);
    float a0 = __uint_as_float((unsigned)rdl((int)hv, 2));   // hoisted tanh-count / dummy bias
    float a1 = 0.f;
    const int c1 = hx & 255, c2 = (hx >> 8) & 255, c3 = (hx >> 16) & 255, c4 = (int)(hx >> 24);
    const int c5 = hy & 255, c6 = (hy >> 8) & 255, c7 = (hy >> 16) & 255, np = (int)(hy >> 24);
    const int m1 = imin(c1, FASTN), m2 = imin(c2, FASTN), m3 = imin(c3, FASTN), m4 = imin(c4, FASTN);
    seg_run4<1,false>(a0, a1, Xl, Hl, hv, 0,  m1);
    seg_run4<2,false>(a0, a1, Xl, Hl, hv, m1, m2);
    seg_run4<3,false>(a0, a1, Xl, Hl, hv, m2, m3);
    seg_run4<4,false>(a0, a1, Xl, Hl, hv, m3, m4);
    if (OUT) {
        const int m5 = imin(c5, FASTN), m6 = imin(c6, FASTN), m7 = imin(c7, FASTN), m8 = imin(np, FASTN);
        seg_run4<1,true>(a0, a1, Xl, Hl, hv, m4, m5);
        seg_run4<2,true>(a0, a1, Xl, Hl, hv, m5, m6);
        seg_run4<3,true>(a0, a1, Xl, Hl, hv, m6, m7);
        seg_run4<4,true>(a0, a1, Xl, Hl, hv, m7, m8);
    }
    if (__builtin_expect(np > FASTN, 0)) {
        // rare overflow: edges FASTN.. at slots 64..; uniform per-edge walk (dummy-safe)
        unsigned hv2 = grow[64 + lane];
        for (int j = FASTN; j < np; ++j) {
            unsigned sp = (unsigned)rdl((int)hv2, j - FASTN);
            int s = (j < c1) ? 0 : (j < c2) ? 1 : (j < c3) ? 2 : (j < c4) ? 3
                  : (j < c5) ? 4 : (j < c6) ? 5 : (j < c7) ? 6 : 7;
            float w = __uint_as_float(sp & 0xFFFFFC00u);
            unsigned off = sp & 1023u;
            float v = (OUT && s >= 4) ? Hl[off * FHS] : bf2f(Xl[off]);
            int a = (s & 3) + 1;
            if (a == 1) a0 = fmaf(v, w, a0);
            else if (a == 2) { float ex = fast_exp2(v * w); a0 += 1.f - 2.f * fast_rcp(1.f + ex); }
            else if (a == 3) a0 += fmaxf(v * w, 0.f);
            else { float ex = fast_exp2(v * w); a0 += fast_rcp(1.f + ex); }
        }
    }
    return a0 + a1;
}

__global__ __launch_bounds__(1024)
void fused_main(const float* __restrict__ x,
                const unsigned* __restrict__ rrh, const unsigned* __restrict__ rro,
                float* __restrict__ out)
{
    extern __shared__ char lds[];
    unsigned short* X   = (unsigned short*)lds;
    float*          Hf  = (float*)(lds + 65792);
    float*          OBT = (float*)lds;                  // overlays X/H after compute
    const int tid  = (int)threadIdx.x;
    const int lane = tid & 63;
    const int wv   = tid >> 6;
    const int rb   = (int)blockIdx.x * 64;
    const unsigned short* Xl = X + (size_t)lane * FXS;
    const float*          Hl = Hf + lane;

    // ---- stage x slab -> bf16 X[64][514], coalesced float4 reads ----
    {
        const float4* xv = (const float4*)(x + (size_t)rb * IN_DIM);
        #pragma unroll
        for (int kk = 0; kk < 8; ++kk) {
            int v = tid + kk * 1024;
            int rr = v >> 7, i = v & 127;
            float4 f = xv[v];
            unsigned int lo = f2bf_rne(f.x) | (f2bf_rne(f.y) << 16);
            unsigned int hi = f2bf_rne(f.z) | (f2bf_rne(f.w) << 16);
            unsigned int* dst = (unsigned int*)&X[rr * FXS + i * 4];
            dst[0] = lo; dst[1] = hi;
        }
    }
    __syncthreads();

    // ---- hidden: wave wv -> rows wv*8..+7, record prefetch pipeline ----
    {
        unsigned hv = rrh[(size_t)(wv * 8) * RSU + lane];
        #pragma unroll 1
        for (int q = 0; q < 8; ++q) {
            const int r = wv * 8 + q;
            unsigned hvn = hv;
            if (q < 7) hvn = rrh[(size_t)(r + 1) * RSU + lane];
            float acc = row_body<false>(hv, rrh + (size_t)r * RSU, Xl, Hl, lane);
            Hf[r * FHS + lane] = acc;
            hv = hvn;
        }
    }
    __syncthreads();

    // ---- output: wave wv -> rows wv*16..+15, results kept in regs ----
    float res[NO / 16];
    {
        unsigned hv = rro[(size_t)(wv * 16) * RSU + lane];
        #pragma unroll 1
        for (int q = 0; q < 16; ++q) {
            const int r = wv * 16 + q;
            unsigned hvn = hv;
            if (q < 15) hvn = rro[(size_t)(r + 1) * RSU + lane];
            res[q] = fast_tanh(row_body<true>(hv, rro + (size_t)r * RSU, Xl, Hl, lane));
            hv = hvn;
        }
    }
    __syncthreads();

    // ---- OBT transpose (stride 65 -> bank = r + lane, conflict-free) ----
    #pragma unroll
    for (int q = 0; q < NO / 16; ++q)
        OBT[(wv * (NO / 16) + q) * FHS + lane] = res[q];
    __syncthreads();
    // lanes read scattered cols (c = lane + i*64 -> bank = lane + b), stores coalesced 256B/wave
    #pragma unroll
    for (int s = 0; s < 4; ++s) {
        const int b = wv * 4 + s;
        #pragma unroll
        for (int i = 0; i < 4; ++i) {
            const int c = lane + i * 64;
            out[(size_t)(rb + b) * NO + c] = OBT[c * FHS + b];
        }
    }
}

// =============== fallback: single fused kernel, no workspace ===============
#define FT      1024
#define FBPB    64
#define FHS2    65
#define FOBTS   260
#define FLDS    (99072 + 1544)
__device__ __forceinline__ float edge_act2(float z, int a, float k) {
    float ex = fast_exp2(k * z);
    float rc = fast_rcp(1.f + ex);
    return (a == 2) ? (1.f - 2.f * rc) : ((a == 4) ? rc : ((a == 3) ? fmaxf(z, 0.f) : z));
}
__global__ __launch_bounds__(FT)
void wann_fused(const float* __restrict__ x,
                const int* __restrict__ rows_h, const int* __restrict__ cols_h,
                const int* __restrict__ acts_h, const float* __restrict__ wh,
                const int* __restrict__ rows_o, const int* __restrict__ cols_o,
                const int* __restrict__ acts_o, const float* __restrict__ wo,
                float* __restrict__ out, int Eh, int Eo)
{
    extern __shared__ char lds[];
    unsigned short* X   = (unsigned short*)lds;
    float*          H   = (float*)(lds + 65792);
    float*          OBT = (float*)lds;
    int*            offsH = (int*)(lds + 99072);
    int*            offsO = offsH + (NH + 1);
    const int tid  = threadIdx.x;
    const int lane = tid & 63;
    const int wv   = tid >> 6;
    const int rb   = blockIdx.x * FBPB;
    const int* wh_i = (const int*)wh;
    const int* wo_i = (const int*)wo;
    {
        const float4* xv = (const float4*)(x + (size_t)rb * IN_DIM);
        #pragma unroll
        for (int kk = 0; kk < (FBPB * IN_DIM / 4) / FT; ++kk) {
            int v = tid + kk * FT;
            int r = v >> 7, i = v & 127;
            float4 f = xv[v];
            unsigned int lo = (unsigned int)f2bf16s(f.x) | ((unsigned int)f2bf16s(f.y) << 16);
            unsigned int hi = (unsigned int)f2bf16s(f.z) | ((unsigned int)f2bf16s(f.w) << 16);
            unsigned int* dst = (unsigned int*)&X[r * FXS + i * 4];
            dst[0] = lo; dst[1] = hi;
        }
    }
    if (tid <= NH) offsH[tid] = lower_bound_dev(rows_h, Eh, tid);
    else if (tid <= NH + 1 + NO) offsO[tid - (NH + 1)] = lower_bound_dev(rows_o, Eo, tid - (NH + 1));
    __syncthreads();
    for (int r = wv * (NH / 16); r < (wv + 1) * (NH / 16); ++r) {
        const int e0 = rfl(offsH[r]); const int e1 = rfl(offsH[r + 1]);
        float acc = 0.f;
        #pragma unroll 4
        for (int e = e0; e < e1; ++e) {
            int col = rfl(cols_h[e]); int a = rfl(acts_h[e]);
            float w = __int_as_float(rfl(wh_i[e]));
            acc += edge_act2(bf2f(X[lane * FXS + col]) * w, a, act_k(a));
        }
        H[r * FHS2 + lane] = acc;
    }
    __syncthreads();
    float res[NO / 16];
    #pragma unroll
    for (int rr = 0; rr < NO / 16; ++rr) {
        const int r = wv * (NO / 16) + rr;
        const int e0 = rfl(offsO[r]); const int e1 = rfl(offsO[r + 1]);
        float acc = 0.f;
        #pragma unroll 4
        for (int e = e0; e < e1; ++e) {
            int col = rfl(cols_o[e]); int a = rfl(acts_o[e]);
            float w = __int_as_float(rfl(wo_i[e]));
            float v = (col < IN_DIM) ? bf2f(X[lane * FXS + col]) : H[(col - IN_DIM) * FHS2 + lane];
            acc += edge_act2(v * w, a, act_k(a));
        }
        res[rr] = fast_tanh(acc);
    }
    __syncthreads();
    #pragma unroll
    for (int rr = 0; rr < NO / 16; ++rr)
        OBT[lane * FOBTS + wv * (NO / 16) + rr] = res[rr];
    __syncthreads();
    #pragma unroll
    for (int kk = 0; kk < (FBPB * NO / 4) / FT; ++kk) {
        int v = tid + kk * FT;
        int c4 = v & 63, b = v >> 6;
        float4 o = *(const float4*)&OBT[b * FOBTS + c4 * 4];
        *(float4*)&out[(size_t)(rb + b) * NO + c4 * 4] = o;
    }
}

extern "C" void kernel_launch(void* const* d_in, const int* in_sizes, int n_in,
                              void* d_out, int out_size, void* d_ws, size_t ws_size,
                              hipStream_t stream) {
    const float* x      = (const float*)d_in[0];
    const float* wh     = (const float*)d_in[1];
    const float* wo     = (const float*)d_in[2];
    const int*   rows_h = (const int*)d_in[3];
    const int*   cols_h = (const int*)d_in[4];
    const int*   acts_h = (const int*)d_in[5];
    const int*   rows_o = (const int*)d_in[6];
    const int*   cols_o = (const int*)d_in[7];
    const int*   acts_o = (const int*)d_in[8];
    float*       out    = (float*)d_out;

    const int Eh = in_sizes[1];
    const int Eo = in_sizes[2];

    // ws layout: [rrh: NH rows x 512B][rro: NO rows x 512B]
    char*     ws  = (char*)d_ws;
    unsigned* rrh = (unsigned*)ws;
    unsigned* rro = (unsigned*)(ws + (size_t)NH * RSU * 4);
    size_t need = (size_t)(NH + NO) * RSU * 4;

    if (ws_size >= need) {
        prep_rows<<<(NH + NO) * 64 / 512, 512, 0, stream>>>(
            rows_h, cols_h, acts_h, wh, rows_o, cols_o, acts_o, wo,
            Eh, Eo, rrh, rro);
        fused_main<<<BATCH / 64, 1024, MLDS, stream>>>(x, rrh, rro, out);
    } else {
        wann_fused<<<BATCH / FBPB, FT, FLDS, stream>>>(
            x, rows_h, cols_h, acts_h, wh, rows_o, cols_o, acts_o, wo, out, Eh, Eo);
    }
}

// Round 8
// 149.841 us; speedup vs baseline: 1.0186x; 1.0186x over previous
//
#include <hip/hip_runtime.h>
#include <math.h>

// Static graph dims
#define BATCH   16384
#define IN_DIM  512
#define NH      128
#define NO      256
#define L2E     1.4426950408889634f

__device__ __forceinline__ float fast_rcp(float x) { return __builtin_amdgcn_rcpf(x); }
__device__ __forceinline__ float fast_exp2(float x) {
#if __has_builtin(__builtin_amdgcn_exp2f)
    return __builtin_amdgcn_exp2f(x);
#else
    return exp2f(x);
#endif
}
__device__ __forceinline__ int rfl(int v) { return __builtin_amdgcn_readfirstlane(v); }
__device__ __forceinline__ int rdl(int v, int l) { return __builtin_amdgcn_readlane(v, l); }

__device__ __forceinline__ float fast_tanh(float z) {
    float ex = fast_exp2(2.f * L2E * z);
    return 1.f - 2.f * fast_rcp(1.f + ex);
}
__device__ __forceinline__ float act_k(int a) {
    return (a == 2) ? (2.f * L2E) : ((a == 4) ? -L2E : 0.f);
}

__device__ __forceinline__ unsigned int f2bf_rne(float f) {
    unsigned int u = __float_as_uint(f);
    return (u + 0x7FFFu + ((u >> 16) & 1u)) >> 16;
}
__device__ __forceinline__ float bf2f(unsigned short h) { return __uint_as_float(((unsigned int)h) << 16); }
__device__ __forceinline__ unsigned short f2bf16s(float f) { return (unsigned short)f2bf_rne(f); }

__device__ __forceinline__ int lower_bound_dev(const int* __restrict__ arr, int n, int v) {
    int lo = 0, hi = n;
    while (lo < hi) { int m = (lo + hi) >> 1; if (arr[m] < v) lo = m + 1; else hi = m; }
    return lo;
}

#define FXS     514
#define FHS     65
#define MLDS    99072
#define RSU     128     // u32 slots per row record (512 B)
#define FASTN   60      // edges 0..59 at slots 3..62; edges 60.. at slots 64..

// ---------------- prep: per-row records; floor(x4, act-sorted) + mixed tails ----------------
// Edge order: X floors [id|tanh|relu|sig] (each length %4==0), X tail (mixed, act embedded),
//             H floors, H tail.  (hidden rows: X part only)
// hdr slot0: e1|e2<<8|e3<<16|e4<<24  (X floor cumulative ends)
// hdr slot1: e5|e6<<8|e7<<16|e8<<24  (e5 = X tail end; e6..e8 = H floor ends id/tanh/relu)
// hdr slot2: e9|e10<<8               (e9 = H floor sig end; e10 = total n)
// floor edge: [w22|off10]; tail edge: [w20|act2|off10], act2 = a-1. Weights prescaled.
__global__ __launch_bounds__(512)
void prep_rows(const int* __restrict__ rows_h, const int* __restrict__ cols_h,
               const int* __restrict__ acts_h, const float* __restrict__ wh,
               const int* __restrict__ rows_o, const int* __restrict__ cols_o,
               const int* __restrict__ acts_o, const float* __restrict__ wo,
               int Eh, int Eo, unsigned* __restrict__ rrh, unsigned* __restrict__ rro)
{
    const int lane = (int)(threadIdx.x & 63);
    const int wid  = (int)((blockIdx.x * 512 + threadIdx.x) >> 6);
    if (wid >= NH + NO) return;
    const bool isH = wid < NH;
    const int r = isH ? wid : wid - NH;
    const int*   rows = isH ? rows_h : rows_o;
    const int*   cols = isH ? cols_h : cols_o;
    const int*   acts = isH ? acts_h : acts_o;
    const float* ww   = isH ? wh : wo;
    const int    E    = isH ? Eh : Eo;
    unsigned* rec = (isH ? rrh : rro) + (size_t)r * RSU;

    const int e0 = lower_bound_dev(rows, E, r);
    const int e1e = lower_bound_dev(rows, E, r + 1);
    int n = e1e - e0; if (n > 100) n = 100;          // memory-safety clamp (unreachable)
    const unsigned long long lt = (1ull << lane) - 1ull;

    int cnt[8] = {0,0,0,0,0,0,0,0};
    for (int g = 0; g < n; g += 64) {
        int seg = -1;
        if (g + lane < n) {
            int e = e0 + g + lane;
            int a = acts[e];
            int col = cols[e];
            seg = (a - 1) + ((!isH && col >= IN_DIM) ? 4 : 0);
        }
        #pragma unroll
        for (int s = 0; s < 8; ++s) cnt[s] += __popcll(__ballot(seg == s));
    }
    int fl[8], tl[8];
    #pragma unroll
    for (int s = 0; s < 8; ++s) { fl[s] = cnt[s] & ~3; tl[s] = cnt[s] - fl[s]; }
    int e_[11];
    e_[0] = 0;
    e_[1] = fl[0]; e_[2] = e_[1] + fl[1]; e_[3] = e_[2] + fl[2]; e_[4] = e_[3] + fl[3];
    e_[5] = e_[4] + tl[0] + tl[1] + tl[2] + tl[3];
    e_[6] = e_[5] + fl[4]; e_[7] = e_[6] + fl[5]; e_[8] = e_[7] + fl[6]; e_[9] = e_[8] + fl[7];
    e_[10] = e_[9] + tl[4] + tl[5] + tl[6] + tl[7];   // == n

    int fbase[8] = { e_[0], e_[1], e_[2], e_[3], e_[5], e_[6], e_[7], e_[8] };
    int tbase[8];
    tbase[0] = e_[4]; tbase[1] = tbase[0] + tl[0]; tbase[2] = tbase[1] + tl[1]; tbase[3] = tbase[2] + tl[2];
    tbase[4] = e_[9]; tbase[5] = tbase[4] + tl[4]; tbase[6] = tbase[5] + tl[5]; tbase[7] = tbase[6] + tl[6];

    if (lane == 0) {
        rec[0] = (unsigned)e_[1] | ((unsigned)e_[2] << 8) | ((unsigned)e_[3] << 16) | ((unsigned)e_[4] << 24);
        rec[1] = (unsigned)e_[5] | ((unsigned)e_[6] << 8) | ((unsigned)e_[7] << 16) | ((unsigned)e_[8] << 24);
        rec[2] = (unsigned)e_[9] | ((unsigned)e_[10] << 8);
    }

    int pos[8] = {0,0,0,0,0,0,0,0};
    for (int g = 0; g < n; g += 64) {
        int seg = -1, a = 0; unsigned offv = 0, wbits = 0;
        if (g + lane < n) {
            int e = e0 + g + lane;
            a = acts[e];
            int col = cols[e];
            bool hs = (!isH && col >= IN_DIM);
            seg = (a - 1) + (hs ? 4 : 0);
            offv = hs ? (unsigned)(col - IN_DIM) : (unsigned)col;   // < 1024
            float w = ww[e];
            float ws = (a == 2) ? (2.f * L2E) * w : ((a == 4) ? -L2E * w : w);
            wbits = __float_as_uint(ws);
        }
        #pragma unroll
        for (int s = 0; s < 8; ++s) {
            unsigned long long m = __ballot(seg == s);
            if (seg == s) {
                int k = pos[s] + __popcll(m & lt);
                bool isFloor = (k < fl[s]);
                int idx = isFloor ? (fbase[s] + k) : (tbase[s] + (k - fl[s]));
                unsigned payload = isFloor
                    ? (((wbits + 0x200u) & 0xFFFFFC00u) | offv)
                    : (((wbits + 0x800u) & 0xFFFFF000u) | ((unsigned)(a - 1) << 10) | offv);
                rec[idx < FASTN ? 3 + idx : 64 + (idx - FASTN)] = payload;
            }
            pos[s] += __popcll(m);
        }
    }
}

// ---------------- fused main ----------------
// LDS: X bf16 [64][514] = 65792 B + Hf f32 [128][65] = 33280 B -> 99072 B.
// All 24 row records preloaded into registers up front (one vmcnt drain).
// Floors: exact x4 compile-time-act loops (no remainder). Tails: one mixed loop
// per source with act embedded (wave-uniform scalar branches).
template<int ACT>
__device__ __forceinline__ float app(float acc, float v, float w) {
    if (ACT == 1)      return fmaf(v, w, acc);
    else if (ACT == 2) { float ex = fast_exp2(v * w); return fmaf(-2.f, fast_rcp(1.f + ex), acc); }
    else if (ACT == 3) return acc + fmaxf(v * w, 0.f);
    else               { float ex = fast_exp2(v * w); return acc + fast_rcp(1.f + ex); }
}

template<int ACT, bool HS>
__device__ __forceinline__ void seg_run4(float& a0, float& a1,
                                         const unsigned short* __restrict__ Xl,  // X + lane*FXS
                                         const float* __restrict__ Hl,           // Hf + lane
                                         unsigned hv, int lo, int hi)
{
    #pragma unroll 2
    for (int j = lo; j < hi; j += 4) {               // (hi-lo) % 4 == 0 by construction
        unsigned s0 = (unsigned)rdl((int)hv, j + 3);
        unsigned s1 = (unsigned)rdl((int)hv, j + 4);
        unsigned s2 = (unsigned)rdl((int)hv, j + 5);
        unsigned s3 = (unsigned)rdl((int)hv, j + 6);
        float v0 = HS ? Hl[(s0 & 1023u) * FHS] : bf2f(Xl[s0 & 1023u]);
        float v1 = HS ? Hl[(s1 & 1023u) * FHS] : bf2f(Xl[s1 & 1023u]);
        float v2 = HS ? Hl[(s2 & 1023u) * FHS] : bf2f(Xl[s2 & 1023u]);
        float v3 = HS ? Hl[(s3 & 1023u) * FHS] : bf2f(Xl[s3 & 1023u]);
        a0 = app<ACT>(a0, v0, __uint_as_float(s0 & 0xFFFFFC00u));
        a1 = app<ACT>(a1, v1, __uint_as_float(s1 & 0xFFFFFC00u));
        a0 = app<ACT>(a0, v2, __uint_as_float(s2 & 0xFFFFFC00u));
        a1 = app<ACT>(a1, v3, __uint_as_float(s3 & 0xFFFFFC00u));
    }
}

__device__ __forceinline__ float app_mixed(float acc, unsigned p, float v) {
    int a = (int)((p >> 10) & 3u);                   // wave-uniform -> scalar branch
    float w = __uint_as_float(p & 0xFFFFF000u);
    float t = v * w;
    if (a == 0)      acc += t;                       // identity
    else if (a == 2) acc += fmaxf(t, 0.f);           // relu
    else {
        float ex = fast_exp2(t);
        float rc = fast_rcp(1.f + ex);
        acc += (a == 1) ? fmaf(-2.f, rc, 1.f) : rc;  // tanh : sigmoid
    }
    return acc;
}

template<bool HS>
__device__ __forceinline__ void seg_tail(float& a0, float& a1,
                                         const unsigned short* __restrict__ Xl,
                                         const float* __restrict__ Hl,
                                         unsigned hv, int lo, int hi)
{
    int j = lo;
    for (; j + 3 < hi; j += 4) {
        unsigned s0 = (unsigned)rdl((int)hv, j + 3);
        unsigned s1 = (unsigned)rdl((int)hv, j + 4);
        unsigned s2 = (unsigned)rdl((int)hv, j + 5);
        unsigned s3 = (unsigned)rdl((int)hv, j + 6);
        float v0 = HS ? Hl[(s0 & 1023u) * FHS] : bf2f(Xl[s0 & 1023u]);
        float v1 = HS ? Hl[(s1 & 1023u) * FHS] : bf2f(Xl[s1 & 1023u]);
        float v2 = HS ? Hl[(s2 & 1023u) * FHS] : bf2f(Xl[s2 & 1023u]);
        float v3 = HS ? Hl[(s3 & 1023u) * FHS] : bf2f(Xl[s3 & 1023u]);
        a0 = app_mixed(a0, s0, v0);
        a1 = app_mixed(a1, s1, v1);
        a0 = app_mixed(a0, s2, v2);
        a1 = app_mixed(a1, s3, v3);
    }
    if (j + 1 < hi) {                                // 2-3 left: pair
        unsigned s0 = (unsigned)rdl((int)hv, j + 3);
        unsigned s1 = (unsigned)rdl((int)hv, j + 4);
        float v0 = HS ? Hl[(s0 & 1023u) * FHS] : bf2f(Xl[s0 & 1023u]);
        float v1 = HS ? Hl[(s1 & 1023u) * FHS] : bf2f(Xl[s1 & 1023u]);
        a0 = app_mixed(a0, s0, v0);
        a1 = app_mixed(a1, s1, v1);
        j += 2;
    }
    if (j < hi) {
        unsigned s0 = (unsigned)rdl((int)hv, j + 3);
        float v0 = HS ? Hl[(s0 & 1023u) * FHS] : bf2f(Xl[s0 & 1023u]);
        a0 = app_mixed(a0, s0, v0);
    }
}

template<bool OUT>
__device__ __forceinline__ float row_body(unsigned hv, const unsigned* __restrict__ grow,
                                          const unsigned short* __restrict__ Xl,
                                          const float* __restrict__ Hl)
{
    const unsigned hx = (unsigned)rdl((int)hv, 0);
    const unsigned hy = (unsigned)rdl((int)hv, 1);
    const unsigned hz = (unsigned)rdl((int)hv, 2);
    const int b1 = hx & 255, b2 = (hx >> 8) & 255, b3 = (hx >> 16) & 255, b4 = (int)(hx >> 24);
    const int b5 = hy & 255, b6 = (hy >> 8) & 255, b7 = (hy >> 16) & 255, b8 = (int)(hy >> 24);
    const int b9 = hz & 255, b10 = (hz >> 8) & 255;
    if (__builtin_expect(b10 <= FASTN, 1)) {
        // hoisted "+1 per tanh floor edge" (tails compute the +1 inline)
        float a0 = (float)((b2 - b1) + (OUT ? (b7 - b6) : 0));
        float a1 = 0.f;
        seg_run4<1,false>(a0, a1, Xl, Hl, hv, 0,  b1);
        seg_run4<2,false>(a0, a1, Xl, Hl, hv, b1, b2);
        seg_run4<3,false>(a0, a1, Xl, Hl, hv, b2, b3);
        seg_run4<4,false>(a0, a1, Xl, Hl, hv, b3, b4);
        seg_tail<false>(a0, a1, Xl, Hl, hv, b4, b5);
        if (OUT) {
            seg_run4<1,true>(a0, a1, Xl, Hl, hv, b5, b6);
            seg_run4<2,true>(a0, a1, Xl, Hl, hv, b6, b7);
            seg_run4<3,true>(a0, a1, Xl, Hl, hv, b7, b8);
            seg_run4<4,true>(a0, a1, Xl, Hl, hv, b8, b9);
            seg_tail<true>(a0, a1, Xl, Hl, hv, b9, b10);
        }
        return a0 + a1;
    }
    // cold path (row > 60 edges; unreachable in practice): uniform walk
    float a0 = 0.f;
    for (int j = 0; j < b10; ++j) {
        unsigned p = (unsigned)rfl((int)grow[j < FASTN ? 3 + j : 64 + (j - FASTN)]);
        unsigned off = p & 1023u;
        bool isTailX = (j >= b4 && j < b5);
        bool isTailH = (j >= b9);
        bool hsrc = OUT && (j >= b5);
        float v = hsrc ? Hl[off * FHS] : bf2f(Xl[off]);
        int a; float w;
        if (isTailX || isTailH) { a = (int)((p >> 10) & 3u); w = __uint_as_float(p & 0xFFFFF000u); }
        else {
            a = (j < b1) ? 0 : (j < b2) ? 1 : (j < b3) ? 2 : (j < b4) ? 3
              : (j < b6) ? 0 : (j < b7) ? 1 : (j < b8) ? 2 : 3;
            w = __uint_as_float(p & 0xFFFFFC00u);
        }
        float t = v * w;
        if (a == 0) a0 += t;
        else if (a == 2) a0 += fmaxf(t, 0.f);
        else { float ex = fast_exp2(t); float rc = fast_rcp(1.f + ex);
               a0 += (a == 1) ? (1.f - 2.f * rc) : rc; }
    }
    return a0;
}

__global__ __launch_bounds__(1024)
void fused_main(const float* __restrict__ x,
                const unsigned* __restrict__ rrh, const unsigned* __restrict__ rro,
                float* __restrict__ out)
{
    extern __shared__ char lds[];
    unsigned short* X   = (unsigned short*)lds;
    float*          Hf  = (float*)(lds + 65792);
    float*          OBT = (float*)lds;                  // overlays X/H after compute
    const int tid  = (int)threadIdx.x;
    const int lane = tid & 63;
    const int wv   = tid >> 6;
    const int rb   = (int)blockIdx.x * 64;
    const unsigned short* Xl = X + (size_t)lane * FXS;
    const float*          Hl = Hf + lane;

    // ---- stage x slab -> bf16 X[64][514], coalesced float4 reads ----
    {
        const float4* xv = (const float4*)(x + (size_t)rb * IN_DIM);
        #pragma unroll
        for (int kk = 0; kk < 8; ++kk) {
            int v = tid + kk * 1024;
            int rr = v >> 7, i = v & 127;
            float4 f = xv[v];
            unsigned int lo = f2bf_rne(f.x) | (f2bf_rne(f.y) << 16);
            unsigned int hi = f2bf_rne(f.z) | (f2bf_rne(f.w) << 16);
            unsigned int* dst = (unsigned int*)&X[rr * FXS + i * 4];
            dst[0] = lo; dst[1] = hi;
        }
    }

    // ---- preload ALL row records into registers (fixed indices; one drain) ----
    unsigned hvh[8], hvo[16];
    #pragma unroll
    for (int q = 0; q < 8; ++q)
        hvh[q] = rrh[(size_t)(wv * 8 + q) * RSU + lane];
    #pragma unroll
    for (int q = 0; q < 16; ++q)
        hvo[q] = rro[(size_t)(wv * 16 + q) * RSU + lane];

    __syncthreads();

    // ---- hidden: wave wv -> rows wv*8..+7 (fully unrolled; records in regs) ----
    #pragma unroll
    for (int q = 0; q < 8; ++q) {
        const int r = wv * 8 + q;
        float acc = row_body<false>(hvh[q], rrh + (size_t)r * RSU, Xl, Hl);
        Hf[r * FHS + lane] = acc;
    }
    __syncthreads();

    // ---- output: wave wv -> rows wv*16..+15, results kept in regs ----
    float res[NO / 16];
    #pragma unroll
    for (int q = 0; q < 16; ++q) {
        const int r = wv * 16 + q;
        res[q] = fast_tanh(row_body<true>(hvo[q], rro + (size_t)r * RSU, Xl, Hl));
    }
    __syncthreads();

    // ---- OBT transpose (stride 65 -> bank = r + lane, conflict-free) ----
    #pragma unroll
    for (int q = 0; q < NO / 16; ++q)
        OBT[(wv * (NO / 16) + q) * FHS + lane] = res[q];
    __syncthreads();
    // lanes read scattered cols (c = lane + i*64 -> bank = lane + b), stores coalesced 256B/wave
    #pragma unroll
    for (int s = 0; s < 4; ++s) {
        const int b = wv * 4 + s;
        #pragma unroll
        for (int i = 0; i < 4; ++i) {
            const int c = lane + i * 64;
            out[(size_t)(rb + b) * NO + c] = OBT[c * FHS + b];
        }
    }
}

// =============== fallback: single fused kernel, no workspace ===============
#define FT      1024
#define FBPB    64
#define FHS2    65
#define FOBTS   260
#define FLDS    (99072 + 1544)
__device__ __forceinline__ float edge_act2(float z, int a, float k) {
    float ex = fast_exp2(k * z);
    float rc = fast_rcp(1.f + ex);
    return (a == 2) ? (1.f - 2.f * rc) : ((a == 4) ? rc : ((a == 3) ? fmaxf(z, 0.f) : z));
}
__global__ __launch_bounds__(FT)
void wann_fused(const float* __restrict__ x,
                const int* __restrict__ rows_h, const int* __restrict__ cols_h,
                const int* __restrict__ acts_h, const float* __restrict__ wh,
                const int* __restrict__ rows_o, const int* __restrict__ cols_o,
                const int* __restrict__ acts_o, const float* __restrict__ wo,
                float* __restrict__ out, int Eh, int Eo)
{
    extern __shared__ char lds[];
    unsigned short* X   = (unsigned short*)lds;
    float*          H   = (float*)(lds + 65792);
    float*          OBT = (float*)lds;
    int*            offsH = (int*)(lds + 99072);
    int*            offsO = offsH + (NH + 1);
    const int tid  = threadIdx.x;
    const int lane = tid & 63;
    const int wv   = tid >> 6;
    const int rb   = blockIdx.x * FBPB;
    const int* wh_i = (const int*)wh;
    const int* wo_i = (const int*)wo;
    {
        const float4* xv = (const float4*)(x + (size_t)rb * IN_DIM);
        #pragma unroll
        for (int kk = 0; kk < (FBPB * IN_DIM / 4) / FT; ++kk) {
            int v = tid + kk * FT;
            int r = v >> 7, i = v & 127;
            float4 f = xv[v];
            unsigned int lo = (unsigned int)f2bf16s(f.x) | ((unsigned int)f2bf16s(f.y) << 16);
            unsigned int hi = (unsigned int)f2bf16s(f.z) | ((unsigned int)f2bf16s(f.w) << 16);
            unsigned int* dst = (unsigned int*)&X[r * FXS + i * 4];
            dst[0] = lo; dst[1] = hi;
        }
    }
    if (tid <= NH) offsH[tid] = lower_bound_dev(rows_h, Eh, tid);
    else if (tid <= NH + 1 + NO) offsO[tid - (NH + 1)] = lower_bound_dev(rows_o, Eo, tid - (NH + 1));
    __syncthreads();
    for (int r = wv * (NH / 16); r < (wv + 1) * (NH / 16); ++r) {
        const int e0 = rfl(offsH[r]); const int e1 = rfl(offsH[r + 1]);
        float acc = 0.f;
        #pragma unroll 4
        for (int e = e0; e < e1; ++e) {
            int col = rfl(cols_h[e]); int a = rfl(acts_h[e]);
            float w = __int_as_float(rfl(wh_i[e]));
            acc += edge_act2(bf2f(X[lane * FXS + col]) * w, a, act_k(a));
        }
        H[r * FHS2 + lane] = acc;
    }
    __syncthreads();
    float res[NO / 16];
    #pragma unroll
    for (int rr = 0; rr < NO / 16; ++rr) {
        const int r = wv * (NO / 16) + rr;
        const int e0 = rfl(offsO[r]); const int e1 = rfl(offsO[r + 1]);
        float acc = 0.f;
        #pragma unroll 4
        for (int e = e0; e < e1; ++e) {
            int col = rfl(cols_o[e]); int a = rfl(acts_o[e]);
            float w = __int_as_float(rfl(wo_i[e]));
            float v = (col < IN_DIM) ? bf2f(X[lane * FXS + col]) : H[(col - IN_DIM) * FHS2 + lane];
            acc += edge_act2(v * w, a, act_k(a));
        }
        res[rr] = fast_tanh(acc);
    }
    __syncthreads();
    #pragma unroll
    for (int rr = 0; rr < NO / 16; ++rr)
        OBT[lane * FOBTS + wv * (NO / 16) + rr] = res[rr];
    __syncthreads();
    #pragma unroll
    for (int kk = 0; kk < (FBPB * NO / 4) / FT; ++kk) {
        int v = tid + kk * FT;
        int c4 = v & 63, b = v >> 6;
        float4 o = *(const float4*)&OBT[b * FOBTS + c4 * 4];
        *(float4*)&out[(size_t)(rb + b) * NO + c4 * 4] = o;
    }
}

extern "C" void kernel_launch(void* const* d_in, const int* in_sizes, int n_in,
                              void* d_out, int out_size, void* d_ws, size_t ws_size,
                              hipStream_t stream) {
    const float* x      = (const float*)d_in[0];
    const float* wh     = (const float*)d_in[1];
    const float* wo     = (const float*)d_in[2];
    const int*   rows_h = (const int*)d_in[3];
    const int*   cols_h = (const int*)d_in[4];
    const int*   acts_h = (const int*)d_in[5];
    const int*   rows_o = (const int*)d_in[6];
    const int*   cols_o = (const int*)d_in[7];
    const int*   acts_o = (const int*)d_in[8];
    float*       out    = (float*)d_out;

    const int Eh = in_sizes[1];
    const int Eo = in_sizes[2];

    // ws layout: [rrh: NH rows x 512B][rro: NO rows x 512B]
    char*     ws  = (char*)d_ws;
    unsigned* rrh = (unsigned*)ws;
    unsigned* rro = (unsigned*)(ws + (size_t)NH * RSU * 4);
    size_t need = (size_t)(NH + NO) * RSU * 4;

    if (ws_size >= need) {
        prep_rows<<<(NH + NO) * 64 / 512, 512, 0, stream>>>(
            rows_h, cols_h, acts_h, wh, rows_o, cols_o, acts_o, wo,
            Eh, Eo, rrh, rro);
        fused_main<<<BATCH / 64, 1024, MLDS, stream>>>(x, rrh, rro, out);
    } else {
        wann_fused<<<BATCH / FBPB, FT, FLDS, stream>>>(
            x, rows_h, cols_h, acts_h, wh, rows_o, cols_o, acts_o, wo, out, Eh, Eo);
    }
}